// Round 14
// baseline (75.366 us; speedup 1.0000x reference)
//
#include <hip/hip_runtime.h>
#include <hip/hip_bf16.h>

typedef __bf16 bf16x8 __attribute__((ext_vector_type(8)));
typedef __bf16 bf16x4 __attribute__((ext_vector_type(4)));
typedef float  f32x16 __attribute__((ext_vector_type(16)));
typedef float  f32x4  __attribute__((ext_vector_type(4)));

#define HD      2048   // H*D floats per token row
#define DH      128
#define KVT     32     // kv tile rows
#define NSPLIT  3
#define NROWS   32768  // Lq*H
#define KTILE_E 4096   // 32x128 bf16 elems (8192 B)
#define KTILE_B 8192
#define VTILE_E 4608   // 128x36 bf16 elems (9216 B; stride-36 -> 2-way = free)
#define VTILE_B 9216

// global_load_lds: LDS dest = wave-uniform base + lane*16 (HW); global src per-lane.
__device__ __forceinline__ void glds16(const void* g, void* l) {
    typedef const __attribute__((address_space(1))) void g_as_t;
    typedef __attribute__((address_space(3))) void l_as_t;
    __builtin_amdgcn_global_load_lds((g_as_t*)g, (l_as_t*)l, 16, 0, 0);
}

// K row-key (R12-proven): bank period is 128B, so only the LOW 3 bits of the
// granule key matter. Rows r, r+8, r+16, r+24 get keys XOR {0,2,4,6} ->
// the 4 lanes aliasing under the 256B row stride hit distinct bank quads.
__device__ __forceinline__ int kkey_of(int r) {
    return (r & 7) ^ (((r >> 3) & 3) << 1);
}

// ---------------------------------------------------------------------------
// Merged prepass. bid < 2048: K[kv][h][d] fp32 -> wsK tile [h][T=kv/32]
// [r=kv&31][granule (c8 ^ kkey_of(r))] bf16. bid >= 2048: V 32x32 LDS
// transpose -> wsV tile [h][T][dv*36 + kv] bf16.
// ---------------------------------------------------------------------------
__global__ __launch_bounds__(256, 4)
void prep_kv(const float* __restrict__ Kg, const float* __restrict__ Vg,
             __bf16* __restrict__ wsK, __bf16* __restrict__ wsV)
{
    __shared__ float tile[32][33];
    const int bid = blockIdx.x;
    if (bid < 2048) {
        const int kv = bid;
        const int t  = threadIdx.x;
        const int h  = t >> 4, c8 = t & 15;
        const float* src = Kg + (size_t)kv * HD + h * DH + c8 * 8;
        f32x4 a = *(const f32x4*)(src);
        f32x4 b = *(const f32x4*)(src + 4);
        bf16x8 o;
        o[0]=(__bf16)a[0]; o[1]=(__bf16)a[1]; o[2]=(__bf16)a[2]; o[3]=(__bf16)a[3];
        o[4]=(__bf16)b[0]; o[5]=(__bf16)b[1]; o[6]=(__bf16)b[2]; o[7]=(__bf16)b[3];
        const int r = kv & 31;
        __bf16* dst = wsK + ((size_t)(h * 64 + (kv >> 5)) * KTILE_E)
                          + r * 128 + ((c8 ^ kkey_of(r)) << 3);
        *(bf16x8*)dst = o;
    } else {
        const int b = bid - 2048;
        const int dvb = b & 3, kvb = (b >> 2) & 63, h = b >> 8;  // kvb == tile idx
        const int t = threadIdx.x;
        {
            const int kvl = t >> 3, dv4 = (t & 7) * 4;
            f32x4 v = *(const f32x4*)(Vg + (size_t)(kvb * 32 + kvl) * HD + h * DH + dvb * 32 + dv4);
            tile[kvl][dv4 + 0] = v[0]; tile[kvl][dv4 + 1] = v[1];
            tile[kvl][dv4 + 2] = v[2]; tile[kvl][dv4 + 3] = v[3];
        }
        __syncthreads();
        {
            const int dvl = t >> 3, kv4 = (t & 7) * 4;   // kv4 0..28
            const int dv = dvb * 32 + dvl;
            bf16x4 o;
            o[0] = (__bf16)tile[kv4 + 0][dvl]; o[1] = (__bf16)tile[kv4 + 1][dvl];
            o[2] = (__bf16)tile[kv4 + 2][dvl]; o[3] = (__bf16)tile[kv4 + 3][dvl];
            __bf16* dst = wsV + ((size_t)(h * 64 + kvb) * VTILE_E) + dv * 36 + kv4;
            *(bf16x4*)dst = o;
        }
    }
}

// ---------------------------------------------------------------------------
// Main attention: 256 thr = 4 warps x 32 q = 128 q/block; KVT=32; grid 768 =
// 16 qb x 48 grp (grp = b % 48 — R13's `b & 47` bug fixed) = 3 blocks/CU
// (LDS 34KB x3 = 102KB; launch_bounds(256,3) caps regs at 170 -> 3 waves/
// SIMD). Hypothesis: the 3rd wave hides the QK->softmax->PV dep chain that
// R12's pipe audit showed serialized at 2 waves/SIMD.
// Staging = linear glds of pre-swizzled bf16 tiles. Partials in bf16.
// NCH per split: {22,21,21} tiles of 32 kv. XCD = b%8 = grp%8 (48 ≡ 0 mod 8).
// ---------------------------------------------------------------------------
__global__ __launch_bounds__(256, 3)
void fmha_main(const float* __restrict__ Qg,
               const __bf16* __restrict__ wsK, const __bf16* __restrict__ wsV,
               __bf16* __restrict__ wsOb, float* __restrict__ wsML)
{
    __shared__ __align__(16) __bf16 klds[2][KTILE_E];   // 8 KB each
    __shared__ __align__(16) __bf16 vlds[2][VTILE_E];   // 9 KB each

    const int tid  = threadIdx.x;
    const int lane = tid & 63;
    const int wrp  = tid >> 6;
    const int g    = lane >> 5;
    const int l31  = lane & 31;

    const int b    = blockIdx.x;
    const int grp  = b % 48;          // XCD = grp%8; qb-siblings share KV in L2
    const int qb   = b / 48;          // 0..15
    const int h    = grp / 3;
    const int sp   = grp % 3;
    const int t0   = (sp == 0) ? 0 : (22 + 21 * (sp - 1));
    const int nch  = (sp == 0) ? 22 : 21;

    const float qscale = 1.4426950408889634f * 0.08838834764831845f; // log2(e)/sqrt(128)
    const int q = qb * 128 + wrp * 32 + l31;

    // ---- Q fragments (B-operand of QK^T): lane=q-row, d = j*16 + 8g + e
    bf16x8 qf[8];
    {
        const float* qrow = Qg + (size_t)q * HD + h * DH;
        #pragma unroll
        for (int j = 0; j < 8; ++j) {
            f32x4 a = *(const f32x4*)(qrow + j * 16 + 8 * g);
            f32x4 c = *(const f32x4*)(qrow + j * 16 + 8 * g + 4);
            bf16x8 f;
            f[0] = (__bf16)(a[0] * qscale); f[1] = (__bf16)(a[1] * qscale);
            f[2] = (__bf16)(a[2] * qscale); f[3] = (__bf16)(a[3] * qscale);
            f[4] = (__bf16)(c[0] * qscale); f[5] = (__bf16)(c[1] * qscale);
            f[6] = (__bf16)(c[2] * qscale); f[7] = (__bf16)(c[3] * qscale);
            qf[j] = f;
        }
    }

    // ---- staging: linear glds copies. K 8KB = 2 chunks/warp; V 9KB = 2 + warp0 tail.
    auto stage = [&](int T, int buf) {
        const char* kt = (const char*)wsK + (size_t)(h * 64 + T) * KTILE_B + wrp * 1024 + lane * 16;
        char* kl = (char*)&klds[buf][0] + wrp * 1024;
        glds16(kt, kl);
        glds16(kt + 4096, kl + 4096);
        const char* vt = (const char*)wsV + (size_t)(h * 64 + T) * VTILE_B + wrp * 1024 + lane * 16;
        char* vl = (char*)&vlds[buf][0] + wrp * 1024;
        glds16(vt, vl);
        glds16(vt + 4096, vl + 4096);
        if (wrp == 0) glds16(vt + 8192, vl + 8192);
    };

    auto sync_all = []() {
        asm volatile("s_waitcnt vmcnt(0) lgkmcnt(0)" ::: "memory");
        __builtin_amdgcn_s_barrier();
    };

    float mrun = -1e30f, lrun = 0.0f;
    f32x16 o0, o1, o2, o3;
    #pragma unroll
    for (int r = 0; r < 16; ++r) { o0[r] = 0.f; o1[r] = 0.f; o2[r] = 0.f; o3[r] = 0.f; }

    stage(t0, 0);
    sync_all();

    const int kkey = kkey_of(l31);

    #pragma unroll 2
    for (int tt = 0; tt < nch; ++tt) {
        const int cur = tt & 1;
        if (tt + 1 < nch) stage(t0 + tt + 1, cur ^ 1);   // issue-early, full-iter cover

        // ---- QK^T (swapped): S^T[kv][q]; 2 independent 4-deep chains over d
        f32x16 sa, sb;
        #pragma unroll
        for (int r = 0; r < 16; ++r) { sa[r] = 0.f; sb[r] = 0.f; }
        __builtin_amdgcn_s_setprio(1);
        #pragma unroll
        for (int j = 0; j < 4; ++j) {
            bf16x8 ka = *(const bf16x8*)&klds[cur][l31 * 128 + (((2*j       + g) ^ kkey) << 3)];
            sa = __builtin_amdgcn_mfma_f32_32x32x16_bf16(ka, qf[j],     sa, 0, 0, 0);
            bf16x8 kb = *(const bf16x8*)&klds[cur][l31 * 128 + (((2*(j+4) + g) ^ kkey) << 3)];
            sb = __builtin_amdgcn_mfma_f32_32x32x16_bf16(kb, qf[j + 4], sb, 0, 0, 0);
        }
        __builtin_amdgcn_s_setprio(0);
        f32x16 s;
        #pragma unroll
        for (int r = 0; r < 16; ++r) s[r] = sa[r] + sb[r];

        // ---- online softmax, T13 defer-max (base-2, P <= 2^8)
        float m8[8];
        #pragma unroll
        for (int r = 0; r < 8; ++r) m8[r] = fmaxf(s[r], s[r + 8]);
        float tmax = fmaxf(fmaxf(fmaxf(m8[0], m8[4]), fmaxf(m8[1], m8[5])),
                           fmaxf(fmaxf(m8[2], m8[6]), fmaxf(m8[3], m8[7])));
        tmax = fmaxf(tmax, __shfl_xor(tmax, 32, 64));

        if (__any(tmax > mrun + 8.0f)) {
            const float mnew  = fmaxf(mrun, tmax);
            const float alpha = __builtin_amdgcn_exp2f(mrun - mnew);
            lrun *= alpha;
            #pragma unroll
            for (int r = 0; r < 16; ++r) { o0[r]*=alpha; o1[r]*=alpha; o2[r]*=alpha; o3[r]*=alpha; }
            mrun = mnew;
        }

        #pragma unroll
        for (int r = 0; r < 16; ++r) s[r] = __builtin_amdgcn_exp2f(s[r] - mrun);
        float ps = 0.f;
        #pragma unroll
        for (int r = 0; r < 16; ++r) ps += s[r];
        lrun += ps;

        // P -> bf16 (S^T C/D reg order == PV B-slot order, verified bijection)
        bf16x8 pf0, pf1;
        #pragma unroll
        for (int e = 0; e < 8; ++e) { pf0[e] = (__bf16)s[e]; pf1[e] = (__bf16)s[8 + e]; }

        // ---- PV: O^T[dv][q] += V^T[dv][kv] * P^T[kv][q]; V rows stride 36 (2-way free)
        __builtin_amdgcn_s_setprio(1);
        #pragma unroll
        for (int bb = 0; bb < 4; ++bb) {
            const __bf16* vb = &vlds[cur][(bb * 32 + l31) * 36];
            f32x16& oo = (bb == 0) ? o0 : (bb == 1) ? o1 : (bb == 2) ? o2 : o3;
            bf16x4 a0 = *(const bf16x4*)(vb + 4 * g);
            bf16x4 a1 = *(const bf16x4*)(vb + 8 + 4 * g);
            bf16x8 va;
            va[0]=a0[0]; va[1]=a0[1]; va[2]=a0[2]; va[3]=a0[3];
            va[4]=a1[0]; va[5]=a1[1]; va[6]=a1[2]; va[7]=a1[3];
            oo = __builtin_amdgcn_mfma_f32_32x32x16_bf16(va, pf0, oo, 0, 0, 0);
            bf16x4 b0 = *(const bf16x4*)(vb + 16 + 4 * g);
            bf16x4 b1 = *(const bf16x4*)(vb + 24 + 4 * g);
            va[0]=b0[0]; va[1]=b0[1]; va[2]=b0[2]; va[3]=b0[3];
            va[4]=b1[0]; va[5]=b1[1]; va[6]=b1[2]; va[7]=b1[3];
            oo = __builtin_amdgcn_mfma_f32_32x32x16_bf16(va, pf1, oo, 0, 0, 0);
        }
        __builtin_amdgcn_s_setprio(0);

        if (tt + 1 < nch) sync_all();
    }

    // ---- epilogue: unnormalized O' (bf16) + (m,l) to workspace
    const float ltot  = lrun + __shfl_xor(lrun, 32, 64);
    const int   rowid = q * 16 + h;

    __bf16* orow = wsOb + ((size_t)sp * NROWS + rowid) * 128;
    #pragma unroll
    for (int bb = 0; bb < 4; ++bb) {
        const f32x16& oo = (bb == 0) ? o0 : (bb == 1) ? o1 : (bb == 2) ? o2 : o3;
        #pragma unroll
        for (int jj = 0; jj < 4; ++jj) {
            bf16x4 v;
            v[0] = (__bf16)oo[4*jj+0]; v[1] = (__bf16)oo[4*jj+1];
            v[2] = (__bf16)oo[4*jj+2]; v[3] = (__bf16)oo[4*jj+3];
            *(bf16x4*)(orow + bb * 32 + 8 * jj + 4 * g) = v;
        }
    }
    if (lane < 32) {
        float* ml = wsML + ((size_t)sp * NROWS + rowid) * 2;
        ml[0] = mrun;
        ml[1] = ltot;
    }
}

// ---------------------------------------------------------------------------
// Combine: O[row] = sum_s 2^(m_s - M) * O'_s[row] / L   (O' in bf16).
// ---------------------------------------------------------------------------
__global__ __launch_bounds__(256, 4)
void fmha_combine(const __bf16* __restrict__ wsOb, const float* __restrict__ wsML,
                  float* __restrict__ Og)
{
    const int tid   = threadIdx.x;
    const int rowid = blockIdx.x * 8 + (tid >> 5);
    const int c     = (tid & 31) * 4;

    float m[NSPLIT], l[NSPLIT];
    float M = -1e30f;
    #pragma unroll
    for (int s = 0; s < NSPLIT; ++s) {
        const float* ml = wsML + ((size_t)s * NROWS + rowid) * 2;
        m[s] = ml[0]; l[s] = ml[1];
        M = fmaxf(M, m[s]);
    }
    float L = 0.f, w[NSPLIT];
    #pragma unroll
    for (int s = 0; s < NSPLIT; ++s) {
        w[s] = __builtin_amdgcn_exp2f(m[s] - M);
        L += l[s] * w[s];
    }
    const float inv = 1.0f / L;

    f32x4 acc; acc[0]=0.f; acc[1]=0.f; acc[2]=0.f; acc[3]=0.f;
    #pragma unroll
    for (int s = 0; s < NSPLIT; ++s) {
        bf16x4 v = *(const bf16x4*)(wsOb + ((size_t)s * NROWS + rowid) * 128 + c);
        acc[0] += (float)v[0] * w[s]; acc[1] += (float)v[1] * w[s];
        acc[2] += (float)v[2] * w[s]; acc[3] += (float)v[3] * w[s];
    }
    f32x4 r;
    r[0] = acc[0]*inv; r[1] = acc[1]*inv; r[2] = acc[2]*inv; r[3] = acc[3]*inv;
    *(f32x4*)(Og + (size_t)rowid * 128 + c) = r;
}

// ---------------------------------------------------------------------------
// Fallback (ws too small — not expected): R1-style single-pass kernel.
// ---------------------------------------------------------------------------
__global__ __launch_bounds__(256, 2)
void fmha_fb(const float* __restrict__ Qg, const float* __restrict__ Kg,
             const float* __restrict__ Vg, float* __restrict__ Og)
{
    __shared__ __align__(16) __bf16 klds[2][32 * 128];
    __shared__ __align__(16) __bf16 vtlds[2][DH * 36];

    const int tid  = threadIdx.x;
    const int lane = tid & 63;
    const int wrp  = tid >> 6;
    const int g    = lane >> 5;
    const int l31  = lane & 31;

    const int b    = blockIdx.x;
    const int h    = 2 * (b & 7) + ((b >> 3) >> 4);
    const int qblk = (b >> 3) & 15;

    const float qscale = 1.4426950408889634f * 0.08838834764831845f;
    const int q = qblk * 128 + wrp * 32 + l31;

    bf16x8 qf[8];
    {
        const float* qrow = Qg + (size_t)q * HD + h * DH;
        #pragma unroll
        for (int db = 0; db < 8; ++db) {
            f32x4 a = *(const f32x4*)(qrow + db * 16 + 8 * g);
            f32x4 c = *(const f32x4*)(qrow + db * 16 + 8 * g + 4);
            bf16x8 f;
            f[0] = (__bf16)(a[0] * qscale); f[1] = (__bf16)(a[1] * qscale);
            f[2] = (__bf16)(a[2] * qscale); f[3] = (__bf16)(a[3] * qscale);
            f[4] = (__bf16)(c[0] * qscale); f[5] = (__bf16)(c[1] * qscale);
            f[6] = (__bf16)(c[2] * qscale); f[7] = (__bf16)(c[3] * qscale);
            qf[db] = f;
        }
    }

    const int krow = tid >> 3, kc = tid & 7;
    const int vkv  = tid & 31, vdv0 = (tid >> 5) * 16;
    const float* kbase = Kg + (size_t)h * DH;
    const float* vbase = Vg + (size_t)h * DH;

    f32x4 kreg0, kreg1, kreg2, kreg3, vreg0, vreg1, vreg2, vreg3;

    auto stage_load = [&](int t) {
        const float* kp = kbase + (size_t)(t * 32 + krow) * HD + kc * 8;
        kreg0 = *(const f32x4*)(kp);
        kreg1 = *(const f32x4*)(kp + 4);
        kreg2 = *(const f32x4*)(kp + 64);
        kreg3 = *(const f32x4*)(kp + 68);
        const float* vp = vbase + (size_t)(t * 32 + vkv) * HD + vdv0;
        vreg0 = *(const f32x4*)(vp);
        vreg1 = *(const f32x4*)(vp + 4);
        vreg2 = *(const f32x4*)(vp + 8);
        vreg3 = *(const f32x4*)(vp + 12);
    };

    auto stage_write = [&](int buf) {
        bf16x8 k0, k1;
        k0[0]=(__bf16)kreg0[0]; k0[1]=(__bf16)kreg0[1]; k0[2]=(__bf16)kreg0[2]; k0[3]=(__bf16)kreg0[3];
        k0[4]=(__bf16)kreg1[0]; k0[5]=(__bf16)kreg1[1]; k0[6]=(__bf16)kreg1[2]; k0[7]=(__bf16)kreg1[3];
        k1[0]=(__bf16)kreg2[0]; k1[1]=(__bf16)kreg2[1]; k1[2]=(__bf16)kreg2[2]; k1[3]=(__bf16)kreg2[3];
        k1[4]=(__bf16)kreg3[0]; k1[5]=(__bf16)kreg3[1]; k1[6]=(__bf16)kreg3[2]; k1[7]=(__bf16)kreg3[3];
        const int swz = (krow & 7) << 3;
        *(bf16x8*)&klds[buf][krow * 128 + ((kc * 8) ^ swz)]      = k0;
        *(bf16x8*)&klds[buf][krow * 128 + ((kc * 8 + 64) ^ swz)] = k1;
        #pragma unroll
        for (int jj = 0; jj < 4; ++jj) {
            f32x4 vv = (jj == 0) ? vreg0 : (jj == 1) ? vreg1 : (jj == 2) ? vreg2 : vreg3;
            #pragma unroll
            for (int e = 0; e < 4; ++e)
                vtlds[buf][(vdv0 + jj * 4 + e) * 36 + vkv] = (__bf16)vv[e];
        }
    };

    float mrun = -1e30f, lrun = 0.0f;
    f32x16 o0, o1, o2, o3;
    #pragma unroll
    for (int r = 0; r < 16; ++r) { o0[r] = 0.f; o1[r] = 0.f; o2[r] = 0.f; o3[r] = 0.f; }

    stage_load(0);
    stage_write(0);

    for (int tt = 0; tt < 64; ++tt) {
        const int cur = tt & 1;
        if (tt + 1 < 64) stage_load(tt + 1);
        __syncthreads();

        f32x16 sa, sb;
        #pragma unroll
        for (int r = 0; r < 16; ++r) { sa[r] = 0.f; sb[r] = 0.f; }
        const int kswz = (l31 & 7) << 3;
        #pragma unroll
        for (int db = 0; db < 4; ++db) {
            bf16x8 kfa = *(const bf16x8*)&klds[cur][l31 * 128 + (((2*db)   * 16 + g * 8) ^ kswz)];
            sa = __builtin_amdgcn_mfma_f32_32x32x16_bf16(kfa, qf[2*db],   sa, 0, 0, 0);
            bf16x8 kfb = *(const bf16x8*)&klds[cur][l31 * 128 + (((2*db+1) * 16 + g * 8) ^ kswz)];
            sb = __builtin_amdgcn_mfma_f32_32x32x16_bf16(kfb, qf[2*db+1], sb, 0, 0, 0);
        }
        f32x16 s;
        #pragma unroll
        for (int r = 0; r < 16; ++r) s[r] = sa[r] + sb[r];

        float m8[8];
        #pragma unroll
        for (int r = 0; r < 8; ++r) m8[r] = fmaxf(s[r], s[r + 8]);
        float tmax = fmaxf(fmaxf(fmaxf(m8[0], m8[4]), fmaxf(m8[1], m8[5])),
                           fmaxf(fmaxf(m8[2], m8[6]), fmaxf(m8[3], m8[7])));
        tmax = fmaxf(tmax, __shfl_xor(tmax, 32, 64));

        if (__any(tmax > mrun + 8.0f)) {
            const float mnew  = fmaxf(mrun, tmax);
            const float alpha = __builtin_amdgcn_exp2f(mrun - mnew);
            lrun *= alpha;
            #pragma unroll
            for (int r = 0; r < 16; ++r) { o0[r] *= alpha; o1[r] *= alpha; o2[r] *= alpha; o3[r] *= alpha; }
            mrun = mnew;
        }

        float p[16];
        #pragma unroll
        for (int r = 0; r < 16; ++r) p[r] = __builtin_amdgcn_exp2f(s[r] - mrun);
        float ps0 = 0, ps1 = 0, ps2 = 0, ps3 = 0;
        #pragma unroll
        for (int r = 0; r < 4; ++r) { ps0 += p[r]; ps1 += p[r+4]; ps2 += p[r+8]; ps3 += p[r+12]; }
        lrun += ((ps0 + ps1) + (ps2 + ps3));

        bf16x8 pf0, pf1;
        #pragma unroll
        for (int e = 0; e < 8; ++e) { pf0[e] = (__bf16)p[e]; pf1[e] = (__bf16)p[8 + e]; }

        #pragma unroll
        for (int bb = 0; bb < 4; ++bb) {
            const __bf16* vb = &vtlds[cur][(bb * 32 + l31) * 36];
            bf16x4 a0 = *(const bf16x4*)(vb + 4 * g);
            bf16x4 a1 = *(const bf16x4*)(vb + 8 + 4 * g);
            bf16x8 va;
            va[0]=a0[0]; va[1]=a0[1]; va[2]=a0[2]; va[3]=a0[3];
            va[4]=a1[0]; va[5]=a1[1]; va[6]=a1[2]; va[7]=a1[3];
            f32x16& oo = (bb == 0) ? o0 : (bb == 1) ? o1 : (bb == 2) ? o2 : o3;
            oo = __builtin_amdgcn_mfma_f32_32x32x16_bf16(va, pf0, oo, 0, 0, 0);
            bf16x4 b0 = *(const bf16x4*)(vb + 16 + 4 * g);
            bf16x4 b1 = *(const bf16x4*)(vb + 24 + 4 * g);
            va[0]=b0[0]; va[1]=b0[1]; va[2]=b0[2]; va[3]=b0[3];
            va[4]=b1[0]; va[5]=b1[1]; va[6]=b1[2]; va[7]=b1[3];
            oo = __builtin_amdgcn_mfma_f32_32x32x16_bf16(va, pf1, oo, 0, 0, 0);
        }

        if (tt + 1 < 64) stage_write(cur ^ 1);
    }

    const float ltot = lrun + __shfl_xor(lrun, 32, 64);
    const float inv  = 1.0f / ltot;
    float* orow = Og + ((size_t)q * 16 + h) * 128;
    #pragma unroll
    for (int bb = 0; bb < 4; ++bb) {
        const f32x16& oo = (bb == 0) ? o0 : (bb == 1) ? o1 : (bb == 2) ? o2 : o3;
        #pragma unroll
        for (int jj = 0; jj < 4; ++jj) {
            f32x4 v;
            v[0] = oo[4*jj+0] * inv; v[1] = oo[4*jj+1] * inv;
            v[2] = oo[4*jj+2] * inv; v[3] = oo[4*jj+3] * inv;
            *(f32x4*)(orow + bb * 32 + 8 * jj + 4 * g) = v;
        }
    }
}

extern "C" void kernel_launch(void* const* d_in, const int* in_sizes, int n_in,
                              void* d_out, int out_size, void* d_ws, size_t ws_size,
                              hipStream_t stream) {
    const float* Q = (const float*)d_in[0];
    const float* K = (const float*)d_in[1];
    const float* V = (const float*)d_in[2];
    float* O = (float*)d_out;

    const size_t wsK_b  = (size_t)16 * 64 * KTILE_B;               // 8 MB
    const size_t wsV_b  = (size_t)16 * 64 * VTILE_B;               // 9.2 MB
    const size_t wsOb_b = (size_t)NSPLIT * NROWS * 128 * 2;        // 25.2 MB bf16
    const size_t wsML_b = (size_t)NSPLIT * NROWS * 2 * 4;          // 0.8 MB
    const size_t need_bytes = wsK_b + wsV_b + wsOb_b + wsML_b;

    if (ws_size >= need_bytes) {
        __bf16* wsK  = (__bf16*)d_ws;
        __bf16* wsV  = (__bf16*)((char*)d_ws + wsK_b);
        __bf16* wsOb = (__bf16*)((char*)d_ws + wsK_b + wsV_b);
        float*  wsML = (float*)((char*)d_ws + wsK_b + wsV_b + wsOb_b);
        hipLaunchKernelGGL(prep_kv, dim3(6144), dim3(256), 0, stream, K, V, wsK, wsV);
        hipLaunchKernelGGL(fmha_main, dim3(768), dim3(256), 0, stream,
                           Q, wsK, wsV, wsOb, wsML);
        hipLaunchKernelGGL(fmha_combine, dim3(NROWS / 8), dim3(256), 0, stream,
                           wsOb, wsML, O);
    } else {
        hipLaunchKernelGGL(fmha_fb, dim3(256), dim3(256), 0, stream, Q, K, V, O);
    }
}

// Round 15
// 65.817 us; speedup vs baseline: 1.1451x; 1.1451x over previous
//
#include <hip/hip_runtime.h>
#include <hip/hip_bf16.h>

typedef __bf16 bf16x8 __attribute__((ext_vector_type(8)));
typedef __bf16 bf16x4 __attribute__((ext_vector_type(4)));
typedef __bf16 bf16x2 __attribute__((ext_vector_type(2)));
typedef float  f32x16 __attribute__((ext_vector_type(16)));
typedef float  f32x4  __attribute__((ext_vector_type(4)));

#define HD     2048   // H*D floats per token row
#define DH     128
#define KVT    64     // kv tile
#define NCH    16     // tiles per split half (1024/64)
#define NSPLIT 2
#define NROWS  32768  // Lq*H
#define VSTR   68     // V^T row stride (2-way bank alias = free; R7-proven)

// K row-key (R12-verified): bank period 128B -> only low 3 granule-key bits
// matter; rows r, r+8, r+16, r+24 get keys XOR {0,2,4,6} so the 4 lanes
// aliasing under the 256B row stride hit distinct bank quads.
__device__ __forceinline__ int kkey_of(int r) {
    return (r & 7) ^ (((r >> 3) & 3) << 1);
}

// ---------------------------------------------------------------------------
// Main attention (R7 = session-best structure + verified micro-fixes):
// 512 thr = 8 warps x 32 q = 256 q/block, KVT=64, grid 256 = 8 qblk x
// (16 h x 2 sp); reg-staged (no prepass: R12/R14 showed prepass cost exactly
// cancels its in-kernel savings). Raw-barrier pipeline: QK(cur) ->
// stage_write(t+1) -> stage_load(t+2) -> softmax -> PV -> lgkm+barrier.
// Partials in bf16 (R14-verified numerics) -> cheaper combine.
// ---------------------------------------------------------------------------
__global__ __launch_bounds__(512, 2)
void fmha_kern(const float* __restrict__ Qg, const float* __restrict__ Kg,
               const float* __restrict__ Vg, __bf16* __restrict__ wsOb,
               float* __restrict__ wsML)
{
    __shared__ __align__(16) __bf16 klds[2][KVT * 128];   // 16KB each, kkey-swizzled
    __shared__ __align__(16) __bf16 vtlds[2][DH * VSTR];  // 17KB each, V^T [dv][kv]

    const int tid  = threadIdx.x;
    const int lane = tid & 63;
    const int wrp  = tid >> 6;        // 0..7
    const int g    = lane >> 5;       // half-wave
    const int l31  = lane & 31;

    const int b    = blockIdx.x;
    const int grp  = b & 31;          // XCD = grp % 8
    const int qblk = b >> 5;          // 0..7
    const int h    = grp >> 1;
    const int sp   = grp & 1;
    const int t0   = sp * NCH;

    const float qscale = 1.4426950408889634f * 0.08838834764831845f; // log2(e)/sqrt(128)
    const int q = qblk * 256 + wrp * 32 + l31;

    // ---- Q fragments (B-operand of QK^T): lane=q-row, d = j*16 + 8g + e
    bf16x8 qf[8];
    {
        const float* qrow = Qg + (size_t)q * HD + h * DH;
        #pragma unroll
        for (int j = 0; j < 8; ++j) {
            f32x4 a = *(const f32x4*)(qrow + j * 16 + 8 * g);
            f32x4 c = *(const f32x4*)(qrow + j * 16 + 8 * g + 4);
            bf16x8 f;
            f[0] = (__bf16)(a[0] * qscale); f[1] = (__bf16)(a[1] * qscale);
            f[2] = (__bf16)(a[2] * qscale); f[3] = (__bf16)(a[3] * qscale);
            f[4] = (__bf16)(c[0] * qscale); f[5] = (__bf16)(c[1] * qscale);
            f[6] = (__bf16)(c[2] * qscale); f[7] = (__bf16)(c[3] * qscale);
            qf[j] = f;
        }
    }

    // ---- staging split across 512 threads (64KB fp32 per tile)
    const int krow = tid >> 3, kc = tid & 7;           // K: 64 rows x 8 chunkers x 16 floats
    const int kvp  = tid & 31, vdv0 = (tid >> 5) * 8;  // V: 32 kv-pairs x 16 dv-slices of 8
    const float* kbase = Kg + (size_t)h * DH;
    const float* vbase = Vg + (size_t)h * DH;

    f32x4 kreg0, kreg1, kreg2, kreg3, vreg0, vreg1, vreg2, vreg3;

    auto stage_load = [&](int t) {   // issue global loads only (T14 issue-early)
        const float* kp = kbase + (size_t)(t * KVT + krow) * HD + kc * 16;
        kreg0 = *(const f32x4*)(kp);
        kreg1 = *(const f32x4*)(kp + 4);
        kreg2 = *(const f32x4*)(kp + 8);
        kreg3 = *(const f32x4*)(kp + 12);
        const float* vp = vbase + (size_t)(t * KVT + 2 * kvp) * HD + vdv0;
        vreg0 = *(const f32x4*)(vp);          // kv 2kvp,   dv0..3
        vreg1 = *(const f32x4*)(vp + 4);      // kv 2kvp,   dv4..7
        vreg2 = *(const f32x4*)(vp + HD);     // kv 2kvp+1, dv0..3
        vreg3 = *(const f32x4*)(vp + HD + 4); // kv 2kvp+1, dv4..7
    };

    auto stage_write = [&](int buf) {  // cvt + LDS write (compiler waits vmcnt at first use)
        // K: thread writes granules kc*2, kc*2+1 of row krow (contig 16 floats)
        bf16x8 k0, k1;
        k0[0]=(__bf16)kreg0[0]; k0[1]=(__bf16)kreg0[1]; k0[2]=(__bf16)kreg0[2]; k0[3]=(__bf16)kreg0[3];
        k0[4]=(__bf16)kreg1[0]; k0[5]=(__bf16)kreg1[1]; k0[6]=(__bf16)kreg1[2]; k0[7]=(__bf16)kreg1[3];
        k1[0]=(__bf16)kreg2[0]; k1[1]=(__bf16)kreg2[1]; k1[2]=(__bf16)kreg2[2]; k1[3]=(__bf16)kreg2[3];
        k1[4]=(__bf16)kreg3[0]; k1[5]=(__bf16)kreg3[1]; k1[6]=(__bf16)kreg3[2]; k1[7]=(__bf16)kreg3[3];
        const int key = kkey_of(krow);
        *(bf16x8*)&klds[buf][krow * 128 + (((kc * 2)     ^ key) << 3)] = k0;
        *(bf16x8*)&klds[buf][krow * 128 + (((kc * 2 + 1) ^ key) << 3)] = k1;
        // V: pair-writes (R4-proven): 8x ds_write_b32 instead of 16x u16
        #pragma unroll
        for (int e = 0; e < 8; ++e) {
            bf16x2 w;
            w[0] = (__bf16)((e < 4) ? vreg0[e & 3] : vreg1[e & 3]); // kv 2kvp
            w[1] = (__bf16)((e < 4) ? vreg2[e & 3] : vreg3[e & 3]); // kv 2kvp+1
            *(bf16x2*)&vtlds[buf][(vdv0 + e) * VSTR + 2 * kvp] = w;
        }
    };

    auto block_sync = []() {
        asm volatile("s_waitcnt lgkmcnt(0)" ::: "memory");
        __builtin_amdgcn_s_barrier();
    };

    float mrun = -1e30f, lrun = 0.0f;
    f32x16 o0, o1, o2, o3;
    #pragma unroll
    for (int r = 0; r < 16; ++r) { o0[r] = 0.f; o1[r] = 0.f; o2[r] = 0.f; o3[r] = 0.f; }

    // prologue: tile t0 -> buf0; issue tile t0+1 loads; sync
    stage_load(t0);
    stage_write(0);
    stage_load(t0 + 1);
    block_sync();

    const int kkey = kkey_of(l31);   // rows l31 and 32+l31 share the key

    #pragma unroll 2
    for (int tt = 0; tt < NCH; ++tt) {
        const int cur = tt & 1;

        // ---- QK^T (swapped): S^T[kv][q]; one chained acc per 32-kv slice
        f32x16 s0, s1;
        #pragma unroll
        for (int r = 0; r < 16; ++r) { s0[r] = 0.f; s1[r] = 0.f; }
        __builtin_amdgcn_s_setprio(1);
        #pragma unroll
        for (int j = 0; j < 8; ++j) {
            const int gcol = ((2 * j + g) ^ kkey) << 3;
            bf16x8 kf0 = *(const bf16x8*)&klds[cur][l31 * 128 + gcol];
            s0 = __builtin_amdgcn_mfma_f32_32x32x16_bf16(kf0, qf[j], s0, 0, 0, 0);
            bf16x8 kf1 = *(const bf16x8*)&klds[cur][(32 + l31) * 128 + gcol];
            s1 = __builtin_amdgcn_mfma_f32_32x32x16_bf16(kf1, qf[j], s1, 0, 0, 0);
        }
        __builtin_amdgcn_s_setprio(0);

        // ---- staging for tile tt+1 (regs loaded last iter) + issue tile tt+2
        if (tt + 1 < NCH) stage_write(cur ^ 1);
        if (tt + 2 < NCH) stage_load(t0 + tt + 2);

        // ---- online softmax over 32 regs (64 kv per q-row with partner lane)
        float m16[8];
        #pragma unroll
        for (int r = 0; r < 8; ++r)
            m16[r] = fmaxf(fmaxf(s0[r], s0[r + 8]), fmaxf(s1[r], s1[r + 8]));
        float tmax = fmaxf(fmaxf(fmaxf(m16[0], m16[4]), fmaxf(m16[1], m16[5])),
                           fmaxf(fmaxf(m16[2], m16[6]), fmaxf(m16[3], m16[7])));
        tmax = fmaxf(tmax, __shfl_xor(tmax, 32, 64));

        if (__any(tmax > mrun + 8.0f)) {   // T13 defer-max, P bounded by 2^8
            const float mnew  = fmaxf(mrun, tmax);
            const float alpha = __builtin_amdgcn_exp2f(mrun - mnew);
            lrun *= alpha;
            #pragma unroll
            for (int r = 0; r < 16; ++r) { o0[r]*=alpha; o1[r]*=alpha; o2[r]*=alpha; o3[r]*=alpha; }
            mrun = mnew;
        }

        #pragma unroll
        for (int r = 0; r < 16; ++r) {   // exp in place: s becomes P
            s0[r] = __builtin_amdgcn_exp2f(s0[r] - mrun);
            s1[r] = __builtin_amdgcn_exp2f(s1[r] - mrun);
        }
        float ps = 0.f;
        #pragma unroll
        for (int r = 0; r < 16; ++r) ps += s0[r] + s1[r];
        lrun += ps;

        // P -> bf16; S^T C/D reg order == PV B-operand slot order (verified bijection)
        bf16x8 pfa0, pfa1, pfb0, pfb1;
        #pragma unroll
        for (int e = 0; e < 8; ++e) {
            pfa0[e] = (__bf16)s0[e]; pfa1[e] = (__bf16)s0[8 + e];
            pfb0[e] = (__bf16)s1[e]; pfb1[e] = (__bf16)s1[8 + e];
        }

        // ---- PV: O^T[dv][q] += V^T[dv][kv] * P^T[kv][q]; 4 dv-tiles x 4 kv-quarters
        __builtin_amdgcn_s_setprio(1);
        #pragma unroll
        for (int bb = 0; bb < 4; ++bb) {
            const __bf16* vb = &vtlds[cur][(bb * 32 + l31) * VSTR];
            f32x16& oo = (bb == 0) ? o0 : (bb == 1) ? o1 : (bb == 2) ? o2 : o3;
            bf16x8 va;
            bf16x4 a0, a1;
            a0 = *(const bf16x4*)(vb + 4 * g);
            a1 = *(const bf16x4*)(vb + 8 + 4 * g);
            va[0]=a0[0]; va[1]=a0[1]; va[2]=a0[2]; va[3]=a0[3];
            va[4]=a1[0]; va[5]=a1[1]; va[6]=a1[2]; va[7]=a1[3];
            oo = __builtin_amdgcn_mfma_f32_32x32x16_bf16(va, pfa0, oo, 0, 0, 0);
            a0 = *(const bf16x4*)(vb + 16 + 4 * g);
            a1 = *(const bf16x4*)(vb + 24 + 4 * g);
            va[0]=a0[0]; va[1]=a0[1]; va[2]=a0[2]; va[3]=a0[3];
            va[4]=a1[0]; va[5]=a1[1]; va[6]=a1[2]; va[7]=a1[3];
            oo = __builtin_amdgcn_mfma_f32_32x32x16_bf16(va, pfa1, oo, 0, 0, 0);
            a0 = *(const bf16x4*)(vb + 32 + 4 * g);
            a1 = *(const bf16x4*)(vb + 40 + 4 * g);
            va[0]=a0[0]; va[1]=a0[1]; va[2]=a0[2]; va[3]=a0[3];
            va[4]=a1[0]; va[5]=a1[1]; va[6]=a1[2]; va[7]=a1[3];
            oo = __builtin_amdgcn_mfma_f32_32x32x16_bf16(va, pfb0, oo, 0, 0, 0);
            a0 = *(const bf16x4*)(vb + 48 + 4 * g);
            a1 = *(const bf16x4*)(vb + 56 + 4 * g);
            va[0]=a0[0]; va[1]=a0[1]; va[2]=a0[2]; va[3]=a0[3];
            va[4]=a1[0]; va[5]=a1[1]; va[6]=a1[2]; va[7]=a1[3];
            oo = __builtin_amdgcn_mfma_f32_32x32x16_bf16(va, pfb1, oo, 0, 0, 0);
        }
        __builtin_amdgcn_s_setprio(0);

        if (tt + 1 < NCH) block_sync();
    }

    // ---- epilogue: unnormalized O' (bf16, R14-verified numerics) + (m,l)
    const float ltot  = lrun + __shfl_xor(lrun, 32, 64);
    const int   rowid = q * 16 + h;

    __bf16* orow = wsOb + ((size_t)sp * NROWS + rowid) * 128;
    #pragma unroll
    for (int bb = 0; bb < 4; ++bb) {
        const f32x16& oo = (bb == 0) ? o0 : (bb == 1) ? o1 : (bb == 2) ? o2 : o3;
        #pragma unroll
        for (int jj = 0; jj < 4; ++jj) {
            bf16x4 v;
            v[0] = (__bf16)oo[4*jj+0]; v[1] = (__bf16)oo[4*jj+1];
            v[2] = (__bf16)oo[4*jj+2]; v[3] = (__bf16)oo[4*jj+3];
            *(bf16x4*)(orow + bb * 32 + 8 * jj + 4 * g) = v;
        }
    }
    if (lane < 32) {
        float* ml = wsML + ((size_t)sp * NROWS + rowid) * 2;
        ml[0] = mrun;
        ml[1] = ltot;
    }
}

// ---------------------------------------------------------------------------
// Combine: O[row] = sum_s 2^(m_s - M) * O'_s[row] / L   (O' in bf16).
// ---------------------------------------------------------------------------
__global__ __launch_bounds__(256, 4)
void fmha_combine(const __bf16* __restrict__ wsOb, const float* __restrict__ wsML,
                  float* __restrict__ Og)
{
    const int tid   = threadIdx.x;
    const int rowid = blockIdx.x * 8 + (tid >> 5);
    const int c     = (tid & 31) * 4;

    float m[NSPLIT], l[NSPLIT];
    float M = -1e30f;
    #pragma unroll
    for (int s = 0; s < NSPLIT; ++s) {
        const float* ml = wsML + ((size_t)s * NROWS + rowid) * 2;
        m[s] = ml[0]; l[s] = ml[1];
        M = fmaxf(M, m[s]);
    }
    float L = 0.f, w[NSPLIT];
    #pragma unroll
    for (int s = 0; s < NSPLIT; ++s) {
        w[s] = __builtin_amdgcn_exp2f(m[s] - M);
        L += l[s] * w[s];
    }
    const float inv = 1.0f / L;

    f32x4 acc; acc[0]=0.f; acc[1]=0.f; acc[2]=0.f; acc[3]=0.f;
    #pragma unroll
    for (int s = 0; s < NSPLIT; ++s) {
        bf16x4 v = *(const bf16x4*)(wsOb + ((size_t)s * NROWS + rowid) * 128 + c);
        acc[0] += (float)v[0] * w[s]; acc[1] += (float)v[1] * w[s];
        acc[2] += (float)v[2] * w[s]; acc[3] += (float)v[3] * w[s];
    }
    f32x4 r;
    r[0] = acc[0]*inv; r[1] = acc[1]*inv; r[2] = acc[2]*inv; r[3] = acc[3]*inv;
    *(f32x4*)(Og + (size_t)rowid * 128 + c) = r;
}

// ---------------------------------------------------------------------------
// Fallback (ws too small — not expected): R1-style single-pass kernel.
// ---------------------------------------------------------------------------
__global__ __launch_bounds__(256, 2)
void fmha_fb(const float* __restrict__ Qg, const float* __restrict__ Kg,
             const float* __restrict__ Vg, float* __restrict__ Og)
{
    __shared__ __align__(16) __bf16 klds[2][32 * 128];
    __shared__ __align__(16) __bf16 vtlds[2][DH * 36];

    const int tid  = threadIdx.x;
    const int lane = tid & 63;
    const int wrp  = tid >> 6;
    const int g    = lane >> 5;
    const int l31  = lane & 31;

    const int b    = blockIdx.x;
    const int h    = 2 * (b & 7) + ((b >> 3) >> 4);
    const int qblk = (b >> 3) & 15;

    const float qscale = 1.4426950408889634f * 0.08838834764831845f;
    const int q = qblk * 128 + wrp * 32 + l31;

    bf16x8 qf[8];
    {
        const float* qrow = Qg + (size_t)q * HD + h * DH;
        #pragma unroll
        for (int db = 0; db < 8; ++db) {
            f32x4 a = *(const f32x4*)(qrow + db * 16 + 8 * g);
            f32x4 c = *(const f32x4*)(qrow + db * 16 + 8 * g + 4);
            bf16x8 f;
            f[0] = (__bf16)(a[0] * qscale); f[1] = (__bf16)(a[1] * qscale);
            f[2] = (__bf16)(a[2] * qscale); f[3] = (__bf16)(a[3] * qscale);
            f[4] = (__bf16)(c[0] * qscale); f[5] = (__bf16)(c[1] * qscale);
            f[6] = (__bf16)(c[2] * qscale); f[7] = (__bf16)(c[3] * qscale);
            qf[db] = f;
        }
    }

    const int krow = tid >> 3, kc = tid & 7;
    const int vkv  = tid & 31, vdv0 = (tid >> 5) * 16;
    const float* kbase = Kg + (size_t)h * DH;
    const float* vbase = Vg + (size_t)h * DH;

    f32x4 kreg0, kreg1, kreg2, kreg3, vreg0, vreg1, vreg2, vreg3;

    auto stage_load = [&](int t) {
        const float* kp = kbase + (size_t)(t * 32 + krow) * HD + kc * 8;
        kreg0 = *(const f32x4*)(kp);
        kreg1 = *(const f32x4*)(kp + 4);
        kreg2 = *(const f32x4*)(kp + 64);
        kreg3 = *(const f32x4*)(kp + 68);
        const float* vp = vbase + (size_t)(t * 32 + vkv) * HD + vdv0;
        vreg0 = *(const f32x4*)(vp);
        vreg1 = *(const f32x4*)(vp + 4);
        vreg2 = *(const f32x4*)(vp + 8);
        vreg3 = *(const f32x4*)(vp + 12);
    };

    auto stage_write = [&](int buf) {
        bf16x8 k0, k1;
        k0[0]=(__bf16)kreg0[0]; k0[1]=(__bf16)kreg0[1]; k0[2]=(__bf16)kreg0[2]; k0[3]=(__bf16)kreg0[3];
        k0[4]=(__bf16)kreg1[0]; k0[5]=(__bf16)kreg1[1]; k0[6]=(__bf16)kreg1[2]; k0[7]=(__bf16)kreg1[3];
        k1[0]=(__bf16)kreg2[0]; k1[1]=(__bf16)kreg2[1]; k1[2]=(__bf16)kreg2[2]; k1[3]=(__bf16)kreg2[3];
        k1[4]=(__bf16)kreg3[0]; k1[5]=(__bf16)kreg3[1]; k1[6]=(__bf16)kreg3[2]; k1[7]=(__bf16)kreg3[3];
        const int swz = (krow & 7) << 3;
        *(bf16x8*)&klds[buf][krow * 128 + ((kc * 8) ^ swz)]      = k0;
        *(bf16x8*)&klds[buf][krow * 128 + ((kc * 8 + 64) ^ swz)] = k1;
        #pragma unroll
        for (int jj = 0; jj < 4; ++jj) {
            f32x4 vv = (jj == 0) ? vreg0 : (jj == 1) ? vreg1 : (jj == 2) ? vreg2 : vreg3;
            #pragma unroll
            for (int e = 0; e < 4; ++e)
                vtlds[buf][(vdv0 + jj * 4 + e) * 36 + vkv] = (__bf16)vv[e];
        }
    };

    float mrun = -1e30f, lrun = 0.0f;
    f32x16 o0, o1, o2, o3;
    #pragma unroll
    for (int r = 0; r < 16; ++r) { o0[r] = 0.f; o1[r] = 0.f; o2[r] = 0.f; o3[r] = 0.f; }

    stage_load(0);
    stage_write(0);

    for (int tt = 0; tt < 64; ++tt) {
        const int cur = tt & 1;
        if (tt + 1 < 64) stage_load(tt + 1);
        __syncthreads();

        f32x16 sa, sb;
        #pragma unroll
        for (int r = 0; r < 16; ++r) { sa[r] = 0.f; sb[r] = 0.f; }
        const int kswz = (l31 & 7) << 3;
        #pragma unroll
        for (int db = 0; db < 4; ++db) {
            bf16x8 kfa = *(const bf16x8*)&klds[cur][l31 * 128 + (((2*db)   * 16 + g * 8) ^ kswz)];
            sa = __builtin_amdgcn_mfma_f32_32x32x16_bf16(kfa, qf[2*db],   sa, 0, 0, 0);
            bf16x8 kfb = *(const bf16x8*)&klds[cur][l31 * 128 + (((2*db+1) * 16 + g * 8) ^ kswz)];
            sb = __builtin_amdgcn_mfma_f32_32x32x16_bf16(kfb, qf[2*db+1], sb, 0, 0, 0);
        }
        f32x16 s;
        #pragma unroll
        for (int r = 0; r < 16; ++r) s[r] = sa[r] + sb[r];

        float m8[8];
        #pragma unroll
        for (int r = 0; r < 8; ++r) m8[r] = fmaxf(s[r], s[r + 8]);
        float tmax = fmaxf(fmaxf(fmaxf(m8[0], m8[4]), fmaxf(m8[1], m8[5])),
                           fmaxf(fmaxf(m8[2], m8[6]), fmaxf(m8[3], m8[7])));
        tmax = fmaxf(tmax, __shfl_xor(tmax, 32, 64));

        if (__any(tmax > mrun + 8.0f)) {
            const float mnew  = fmaxf(mrun, tmax);
            const float alpha = __builtin_amdgcn_exp2f(mrun - mnew);
            lrun *= alpha;
            #pragma unroll
            for (int r = 0; r < 16; ++r) { o0[r] *= alpha; o1[r] *= alpha; o2[r] *= alpha; o3[r] *= alpha; }
            mrun = mnew;
        }

        float p[16];
        #pragma unroll
        for (int r = 0; r < 16; ++r) p[r] = __builtin_amdgcn_exp2f(s[r] - mrun);
        float ps0 = 0, ps1 = 0, ps2 = 0, ps3 = 0;
        #pragma unroll
        for (int r = 0; r < 4; ++r) { ps0 += p[r]; ps1 += p[r+4]; ps2 += p[r+8]; ps3 += p[r+12]; }
        lrun += ((ps0 + ps1) + (ps2 + ps3));

        bf16x8 pf0, pf1;
        #pragma unroll
        for (int e = 0; e < 8; ++e) { pf0[e] = (__bf16)p[e]; pf1[e] = (__bf16)p[8 + e]; }

        #pragma unroll
        for (int bb = 0; bb < 4; ++bb) {
            const __bf16* vb = &vtlds[cur][(bb * 32 + l31) * 36];
            bf16x4 a0 = *(const bf16x4*)(vb + 4 * g);
            bf16x4 a1 = *(const bf16x4*)(vb + 8 + 4 * g);
            bf16x8 va;
            va[0]=a0[0]; va[1]=a0[1]; va[2]=a0[2]; va[3]=a0[3];
            va[4]=a1[0]; va[5]=a1[1]; va[6]=a1[2]; va[7]=a1[3];
            f32x16& oo = (bb == 0) ? o0 : (bb == 1) ? o1 : (bb == 2) ? o2 : o3;
            oo = __builtin_amdgcn_mfma_f32_32x32x16_bf16(va, pf0, oo, 0, 0, 0);
            bf16x4 b0 = *(const bf16x4*)(vb + 16 + 4 * g);
            bf16x4 b1 = *(const bf16x4*)(vb + 24 + 4 * g);
            va[0]=b0[0]; va[1]=b0[1]; va[2]=b0[2]; va[3]=b0[3];
            va[4]=b1[0]; va[5]=b1[1]; va[6]=b1[2]; va[7]=b1[3];
            oo = __builtin_amdgcn_mfma_f32_32x32x16_bf16(va, pf1, oo, 0, 0, 0);
        }

        if (tt + 1 < 64) stage_write(cur ^ 1);
    }

    const float ltot = lrun + __shfl_xor(lrun, 32, 64);
    const float inv  = 1.0f / ltot;
    float* orow = Og + ((size_t)q * 16 + h) * 128;
    #pragma unroll
    for (int bb = 0; bb < 4; ++bb) {
        const f32x16& oo = (bb == 0) ? o0 : (bb == 1) ? o1 : (bb == 2) ? o2 : o3;
        #pragma unroll
        for (int jj = 0; jj < 4; ++jj) {
            f32x4 v;
            v[0] = oo[4*jj+0] * inv; v[1] = oo[4*jj+1] * inv;
            v[2] = oo[4*jj+2] * inv; v[3] = oo[4*jj+3] * inv;
            *(f32x4*)(orow + bb * 32 + 8 * jj + 4 * g) = v;
        }
    }
}

extern "C" void kernel_launch(void* const* d_in, const int* in_sizes, int n_in,
                              void* d_out, int out_size, void* d_ws, size_t ws_size,
                              hipStream_t stream) {
    const float* Q = (const float*)d_in[0];
    const float* K = (const float*)d_in[1];
    const float* V = (const float*)d_in[2];
    float* O = (float*)d_out;

    const size_t wsOb_b = (size_t)NSPLIT * NROWS * 128 * 2;   // 16.8 MB bf16
    const size_t wsML_b = (size_t)NSPLIT * NROWS * 2 * 4;     // 0.5 MB
    const size_t need_bytes = wsOb_b + wsML_b;

    if (ws_size >= need_bytes) {
        __bf16* wsOb = (__bf16*)d_ws;
        float*  wsML = (float*)((char*)d_ws + wsOb_b);
        hipLaunchKernelGGL(fmha_kern, dim3(256), dim3(512), 0, stream,
                           Q, K, V, wsOb, wsML);
        hipLaunchKernelGGL(fmha_combine, dim3(NROWS / 8), dim3(256), 0, stream,
                           wsOb, wsML, O);
    } else {
        hipLaunchKernelGGL(fmha_fb, dim3(256), dim3(256), 0, stream, Q, K, V, O);
    }
}

// Round 16
// 65.362 us; speedup vs baseline: 1.1531x; 1.0070x over previous
//
#include <hip/hip_runtime.h>
#include <hip/hip_bf16.h>

typedef __bf16 bf16x8 __attribute__((ext_vector_type(8)));
typedef __bf16 bf16x4 __attribute__((ext_vector_type(4)));
typedef __bf16 bf16x2 __attribute__((ext_vector_type(2)));
typedef float  f32x16 __attribute__((ext_vector_type(16)));
typedef float  f32x4  __attribute__((ext_vector_type(4)));

#define HD     2048   // H*D floats per token row
#define DH     128
#define KVT    64     // kv tile
#define NCH    16     // tiles per split half (1024/64)
#define NSPLIT 2
#define NROWS  32768  // Lq*H
#define VSTR   68     // V^T row stride (2-way bank alias = free; R7-proven)

// K row-key: R7's empirically-best key (R15's quad-spread variant measured
// MORE write-side conflicts, 2.62M vs 2.1M; read-side is identical 4-way
// either way since only low-3 key bits reach the bank index).
__device__ __forceinline__ int kkey_of(int r) {
    return r & 7;
}

// ---------------------------------------------------------------------------
// Main attention (R7 session-best structure + R15's verified bf16 partials):
// 512 thr = 8 warps x 32 q = 256 q/block, KVT=64, grid 256 = 8 qblk x
// (16 h x 2 sp); reg-staged (prepass cost cancels its savings — R12/R14).
// Raw-barrier pipeline: QK(cur) -> stage_write(t+1) -> stage_load(t+2) ->
// softmax -> PV -> lgkm+barrier. Partials in bf16 -> cheap combine.
// ---------------------------------------------------------------------------
__global__ __launch_bounds__(512, 2)
void fmha_kern(const float* __restrict__ Qg, const float* __restrict__ Kg,
               const float* __restrict__ Vg, __bf16* __restrict__ wsOb,
               float* __restrict__ wsML)
{
    __shared__ __align__(16) __bf16 klds[2][KVT * 128];   // 16KB each, key-swizzled
    __shared__ __align__(16) __bf16 vtlds[2][DH * VSTR];  // 17KB each, V^T [dv][kv]

    const int tid  = threadIdx.x;
    const int lane = tid & 63;
    const int wrp  = tid >> 6;        // 0..7
    const int g    = lane >> 5;       // half-wave
    const int l31  = lane & 31;

    const int b    = blockIdx.x;
    const int grp  = b & 31;          // XCD = grp % 8
    const int qblk = b >> 5;          // 0..7
    const int h    = grp >> 1;
    const int sp   = grp & 1;
    const int t0   = sp * NCH;

    const float qscale = 1.4426950408889634f * 0.08838834764831845f; // log2(e)/sqrt(128)
    const int q = qblk * 256 + wrp * 32 + l31;

    // ---- Q fragments (B-operand of QK^T): lane=q-row, d = j*16 + 8g + e
    bf16x8 qf[8];
    {
        const float* qrow = Qg + (size_t)q * HD + h * DH;
        #pragma unroll
        for (int j = 0; j < 8; ++j) {
            f32x4 a = *(const f32x4*)(qrow + j * 16 + 8 * g);
            f32x4 c = *(const f32x4*)(qrow + j * 16 + 8 * g + 4);
            bf16x8 f;
            f[0] = (__bf16)(a[0] * qscale); f[1] = (__bf16)(a[1] * qscale);
            f[2] = (__bf16)(a[2] * qscale); f[3] = (__bf16)(a[3] * qscale);
            f[4] = (__bf16)(c[0] * qscale); f[5] = (__bf16)(c[1] * qscale);
            f[6] = (__bf16)(c[2] * qscale); f[7] = (__bf16)(c[3] * qscale);
            qf[j] = f;
        }
    }

    // ---- staging split across 512 threads (64KB fp32 per tile)
    const int krow = tid >> 3, kc = tid & 7;           // K: 64 rows x 8 chunkers x 16 floats
    const int kvp  = tid & 31, vdv0 = (tid >> 5) * 8;  // V: 32 kv-pairs x 16 dv-slices of 8
    const float* kbase = Kg + (size_t)h * DH;
    const float* vbase = Vg + (size_t)h * DH;

    f32x4 kreg0, kreg1, kreg2, kreg3, vreg0, vreg1, vreg2, vreg3;

    auto stage_load = [&](int t) {   // issue global loads only (T14 issue-early)
        const float* kp = kbase + (size_t)(t * KVT + krow) * HD + kc * 16;
        kreg0 = *(const f32x4*)(kp);
        kreg1 = *(const f32x4*)(kp + 4);
        kreg2 = *(const f32x4*)(kp + 8);
        kreg3 = *(const f32x4*)(kp + 12);
        const float* vp = vbase + (size_t)(t * KVT + 2 * kvp) * HD + vdv0;
        vreg0 = *(const f32x4*)(vp);          // kv 2kvp,   dv0..3
        vreg1 = *(const f32x4*)(vp + 4);      // kv 2kvp,   dv4..7
        vreg2 = *(const f32x4*)(vp + HD);     // kv 2kvp+1, dv0..3
        vreg3 = *(const f32x4*)(vp + HD + 4); // kv 2kvp+1, dv4..7
    };

    auto stage_write = [&](int buf) {  // cvt + LDS write (compiler waits vmcnt at first use)
        bf16x8 k0, k1;
        k0[0]=(__bf16)kreg0[0]; k0[1]=(__bf16)kreg0[1]; k0[2]=(__bf16)kreg0[2]; k0[3]=(__bf16)kreg0[3];
        k0[4]=(__bf16)kreg1[0]; k0[5]=(__bf16)kreg1[1]; k0[6]=(__bf16)kreg1[2]; k0[7]=(__bf16)kreg1[3];
        k1[0]=(__bf16)kreg2[0]; k1[1]=(__bf16)kreg2[1]; k1[2]=(__bf16)kreg2[2]; k1[3]=(__bf16)kreg2[3];
        k1[4]=(__bf16)kreg3[0]; k1[5]=(__bf16)kreg3[1]; k1[6]=(__bf16)kreg3[2]; k1[7]=(__bf16)kreg3[3];
        const int key = kkey_of(krow);
        *(bf16x8*)&klds[buf][krow * 128 + (((kc * 2)     ^ key) << 3)] = k0;
        *(bf16x8*)&klds[buf][krow * 128 + (((kc * 2 + 1) ^ key) << 3)] = k1;
        // V: pair-writes (R4-proven): 8x ds_write_b32 instead of 16x u16
        #pragma unroll
        for (int e = 0; e < 8; ++e) {
            bf16x2 w;
            w[0] = (__bf16)((e < 4) ? vreg0[e & 3] : vreg1[e & 3]); // kv 2kvp
            w[1] = (__bf16)((e < 4) ? vreg2[e & 3] : vreg3[e & 3]); // kv 2kvp+1
            *(bf16x2*)&vtlds[buf][(vdv0 + e) * VSTR + 2 * kvp] = w;
        }
    };

    auto block_sync = []() {
        asm volatile("s_waitcnt lgkmcnt(0)" ::: "memory");
        __builtin_amdgcn_s_barrier();
    };

    float mrun = -1e30f, lrun = 0.0f;
    f32x16 o0, o1, o2, o3;
    #pragma unroll
    for (int r = 0; r < 16; ++r) { o0[r] = 0.f; o1[r] = 0.f; o2[r] = 0.f; o3[r] = 0.f; }

    // prologue: tile t0 -> buf0; issue tile t0+1 loads; sync
    stage_load(t0);
    stage_write(0);
    stage_load(t0 + 1);
    block_sync();

    const int kkey = kkey_of(l31);   // rows l31 and 32+l31 share the key

    #pragma unroll 2
    for (int tt = 0; tt < NCH; ++tt) {
        const int cur = tt & 1;

        // ---- QK^T (swapped): S^T[kv][q]; one chained acc per 32-kv slice
        f32x16 s0, s1;
        #pragma unroll
        for (int r = 0; r < 16; ++r) { s0[r] = 0.f; s1[r] = 0.f; }
        __builtin_amdgcn_s_setprio(1);
        #pragma unroll
        for (int j = 0; j < 8; ++j) {
            const int gcol = ((2 * j + g) ^ kkey) << 3;
            bf16x8 kf0 = *(const bf16x8*)&klds[cur][l31 * 128 + gcol];
            s0 = __builtin_amdgcn_mfma_f32_32x32x16_bf16(kf0, qf[j], s0, 0, 0, 0);
            bf16x8 kf1 = *(const bf16x8*)&klds[cur][(32 + l31) * 128 + gcol];
            s1 = __builtin_amdgcn_mfma_f32_32x32x16_bf16(kf1, qf[j], s1, 0, 0, 0);
        }
        __builtin_amdgcn_s_setprio(0);

        // ---- staging for tile tt+1 (regs loaded last iter) + issue tile tt+2
        if (tt + 1 < NCH) stage_write(cur ^ 1);
        if (tt + 2 < NCH) stage_load(t0 + tt + 2);

        // ---- online softmax over 32 regs (64 kv per q-row with partner lane)
        float m16[8];
        #pragma unroll
        for (int r = 0; r < 8; ++r)
            m16[r] = fmaxf(fmaxf(s0[r], s0[r + 8]), fmaxf(s1[r], s1[r + 8]));
        float tmax = fmaxf(fmaxf(fmaxf(m16[0], m16[4]), fmaxf(m16[1], m16[5])),
                           fmaxf(fmaxf(m16[2], m16[6]), fmaxf(m16[3], m16[7])));
        tmax = fmaxf(tmax, __shfl_xor(tmax, 32, 64));

        if (__any(tmax > mrun + 8.0f)) {   // T13 defer-max, P bounded by 2^8
            const float mnew  = fmaxf(mrun, tmax);
            const float alpha = __builtin_amdgcn_exp2f(mrun - mnew);
            lrun *= alpha;
            #pragma unroll
            for (int r = 0; r < 16; ++r) { o0[r]*=alpha; o1[r]*=alpha; o2[r]*=alpha; o3[r]*=alpha; }
            mrun = mnew;
        }

        #pragma unroll
        for (int r = 0; r < 16; ++r) {   // exp in place: s becomes P
            s0[r] = __builtin_amdgcn_exp2f(s0[r] - mrun);
            s1[r] = __builtin_amdgcn_exp2f(s1[r] - mrun);
        }
        float ps = 0.f;
        #pragma unroll
        for (int r = 0; r < 16; ++r) ps += s0[r] + s1[r];
        lrun += ps;

        // P -> bf16; S^T C/D reg order == PV B-operand slot order (verified bijection)
        bf16x8 pfa0, pfa1, pfb0, pfb1;
        #pragma unroll
        for (int e = 0; e < 8; ++e) {
            pfa0[e] = (__bf16)s0[e]; pfa1[e] = (__bf16)s0[8 + e];
            pfb0[e] = (__bf16)s1[e]; pfb1[e] = (__bf16)s1[8 + e];
        }

        // ---- PV: O^T[dv][q] += V^T[dv][kv] * P^T[kv][q]; 4 dv-tiles x 4 kv-quarters
        __builtin_amdgcn_s_setprio(1);
        #pragma unroll
        for (int bb = 0; bb < 4; ++bb) {
            const __bf16* vb = &vtlds[cur][(bb * 32 + l31) * VSTR];
            f32x16& oo = (bb == 0) ? o0 : (bb == 1) ? o1 : (bb == 2) ? o2 : o3;
            bf16x8 va;
            bf16x4 a0, a1;
            a0 = *(const bf16x4*)(vb + 4 * g);
            a1 = *(const bf16x4*)(vb + 8 + 4 * g);
            va[0]=a0[0]; va[1]=a0[1]; va[2]=a0[2]; va[3]=a0[3];
            va[4]=a1[0]; va[5]=a1[1]; va[6]=a1[2]; va[7]=a1[3];
            oo = __builtin_amdgcn_mfma_f32_32x32x16_bf16(va, pfa0, oo, 0, 0, 0);
            a0 = *(const bf16x4*)(vb + 16 + 4 * g);
            a1 = *(const bf16x4*)(vb + 24 + 4 * g);
            va[0]=a0[0]; va[1]=a0[1]; va[2]=a0[2]; va[3]=a0[3];
            va[4]=a1[0]; va[5]=a1[1]; va[6]=a1[2]; va[7]=a1[3];
            oo = __builtin_amdgcn_mfma_f32_32x32x16_bf16(va, pfa1, oo, 0, 0, 0);
            a0 = *(const bf16x4*)(vb + 32 + 4 * g);
            a1 = *(const bf16x4*)(vb + 40 + 4 * g);
            va[0]=a0[0]; va[1]=a0[1]; va[2]=a0[2]; va[3]=a0[3];
            va[4]=a1[0]; va[5]=a1[1]; va[6]=a1[2]; va[7]=a1[3];
            oo = __builtin_amdgcn_mfma_f32_32x32x16_bf16(va, pfb0, oo, 0, 0, 0);
            a0 = *(const bf16x4*)(vb + 48 + 4 * g);
            a1 = *(const bf16x4*)(vb + 56 + 4 * g);
            va[0]=a0[0]; va[1]=a0[1]; va[2]=a0[2]; va[3]=a0[3];
            va[4]=a1[0]; va[5]=a1[1]; va[6]=a1[2]; va[7]=a1[3];
            oo = __builtin_amdgcn_mfma_f32_32x32x16_bf16(va, pfb1, oo, 0, 0, 0);
        }
        __builtin_amdgcn_s_setprio(0);

        if (tt + 1 < NCH) block_sync();
    }

    // ---- epilogue: unnormalized O' (bf16, R14/R15-verified numerics) + (m,l)
    const float ltot  = lrun + __shfl_xor(lrun, 32, 64);
    const int   rowid = q * 16 + h;

    __bf16* orow = wsOb + ((size_t)sp * NROWS + rowid) * 128;
    #pragma unroll
    for (int bb = 0; bb < 4; ++bb) {
        const f32x16& oo = (bb == 0) ? o0 : (bb == 1) ? o1 : (bb == 2) ? o2 : o3;
        #pragma unroll
        for (int jj = 0; jj < 4; ++jj) {
            bf16x4 v;
            v[0] = (__bf16)oo[4*jj+0]; v[1] = (__bf16)oo[4*jj+1];
            v[2] = (__bf16)oo[4*jj+2]; v[3] = (__bf16)oo[4*jj+3];
            *(bf16x4*)(orow + bb * 32 + 8 * jj + 4 * g) = v;
        }
    }
    if (lane < 32) {
        float* ml = wsML + ((size_t)sp * NROWS + rowid) * 2;
        ml[0] = mrun;
        ml[1] = ltot;
    }
}

// ---------------------------------------------------------------------------
// Combine: O[row] = sum_s 2^(m_s - M) * O'_s[row] / L   (O' in bf16).
// ---------------------------------------------------------------------------
__global__ __launch_bounds__(256, 4)
void fmha_combine(const __bf16* __restrict__ wsOb, const float* __restrict__ wsML,
                  float* __restrict__ Og)
{
    const int tid   = threadIdx.x;
    const int rowid = blockIdx.x * 8 + (tid >> 5);
    const int c     = (tid & 31) * 4;

    float m[NSPLIT], l[NSPLIT];
    float M = -1e30f;
    #pragma unroll
    for (int s = 0; s < NSPLIT; ++s) {
        const float* ml = wsML + ((size_t)s * NROWS + rowid) * 2;
        m[s] = ml[0]; l[s] = ml[1];
        M = fmaxf(M, m[s]);
    }
    float L = 0.f, w[NSPLIT];
    #pragma unroll
    for (int s = 0; s < NSPLIT; ++s) {
        w[s] = __builtin_amdgcn_exp2f(m[s] - M);
        L += l[s] * w[s];
    }
    const float inv = 1.0f / L;

    f32x4 acc; acc[0]=0.f; acc[1]=0.f; acc[2]=0.f; acc[3]=0.f;
    #pragma unroll
    for (int s = 0; s < NSPLIT; ++s) {
        bf16x4 v = *(const bf16x4*)(wsOb + ((size_t)s * NROWS + rowid) * 128 + c);
        acc[0] += (float)v[0] * w[s]; acc[1] += (float)v[1] * w[s];
        acc[2] += (float)v[2] * w[s]; acc[3] += (float)v[3] * w[s];
    }
    f32x4 r;
    r[0] = acc[0]*inv; r[1] = acc[1]*inv; r[2] = acc[2]*inv; r[3] = acc[3]*inv;
    *(f32x4*)(Og + (size_t)rowid * 128 + c) = r;
}

// ---------------------------------------------------------------------------
// Fallback (ws too small — not expected): R1-style single-pass kernel.
// ---------------------------------------------------------------------------
__global__ __launch_bounds__(256, 2)
void fmha_fb(const float* __restrict__ Qg, const float* __restrict__ Kg,
             const float* __restrict__ Vg, float* __restrict__ Og)
{
    __shared__ __align__(16) __bf16 klds[2][32 * 128];
    __shared__ __align__(16) __bf16 vtlds[2][DH * 36];

    const int tid  = threadIdx.x;
    const int lane = tid & 63;
    const int wrp  = tid >> 6;
    const int g    = lane >> 5;
    const int l31  = lane & 31;

    const int b    = blockIdx.x;
    const int h    = 2 * (b & 7) + ((b >> 3) >> 4);
    const int qblk = (b >> 3) & 15;

    const float qscale = 1.4426950408889634f * 0.08838834764831845f;
    const int q = qblk * 128 + wrp * 32 + l31;

    bf16x8 qf[8];
    {
        const float* qrow = Qg + (size_t)q * HD + h * DH;
        #pragma unroll
        for (int db = 0; db < 8; ++db) {
            f32x4 a = *(const f32x4*)(qrow + db * 16 + 8 * g);
            f32x4 c = *(const f32x4*)(qrow + db * 16 + 8 * g + 4);
            bf16x8 f;
            f[0] = (__bf16)(a[0] * qscale); f[1] = (__bf16)(a[1] * qscale);
            f[2] = (__bf16)(a[2] * qscale); f[3] = (__bf16)(a[3] * qscale);
            f[4] = (__bf16)(c[0] * qscale); f[5] = (__bf16)(c[1] * qscale);
            f[6] = (__bf16)(c[2] * qscale); f[7] = (__bf16)(c[3] * qscale);
            qf[db] = f;
        }
    }

    const int krow = tid >> 3, kc = tid & 7;
    const int vkv  = tid & 31, vdv0 = (tid >> 5) * 16;
    const float* kbase = Kg + (size_t)h * DH;
    const float* vbase = Vg + (size_t)h * DH;

    f32x4 kreg0, kreg1, kreg2, kreg3, vreg0, vreg1, vreg2, vreg3;

    auto stage_load = [&](int t) {
        const float* kp = kbase + (size_t)(t * 32 + krow) * HD + kc * 8;
        kreg0 = *(const f32x4*)(kp);
        kreg1 = *(const f32x4*)(kp + 4);
        kreg2 = *(const f32x4*)(kp + 64);
        kreg3 = *(const f32x4*)(kp + 68);
        const float* vp = vbase + (size_t)(t * 32 + vkv) * HD + vdv0;
        vreg0 = *(const f32x4*)(vp);
        vreg1 = *(const f32x4*)(vp + 4);
        vreg2 = *(const f32x4*)(vp + 8);
        vreg3 = *(const f32x4*)(vp + 12);
    };

    auto stage_write = [&](int buf) {
        bf16x8 k0, k1;
        k0[0]=(__bf16)kreg0[0]; k0[1]=(__bf16)kreg0[1]; k0[2]=(__bf16)kreg0[2]; k0[3]=(__bf16)kreg0[3];
        k0[4]=(__bf16)kreg1[0]; k0[5]=(__bf16)kreg1[1]; k0[6]=(__bf16)kreg1[2]; k0[7]=(__bf16)kreg1[3];
        k1[0]=(__bf16)kreg2[0]; k1[1]=(__bf16)kreg2[1]; k1[2]=(__bf16)kreg2[2]; k1[3]=(__bf16)kreg2[3];
        k1[4]=(__bf16)kreg3[0]; k1[5]=(__bf16)kreg3[1]; k1[6]=(__bf16)kreg3[2]; k1[7]=(__bf16)kreg3[3];
        const int swz = (krow & 7) << 3;
        *(bf16x8*)&klds[buf][krow * 128 + ((kc * 8) ^ swz)]      = k0;
        *(bf16x8*)&klds[buf][krow * 128 + ((kc * 8 + 64) ^ swz)] = k1;
        #pragma unroll
        for (int jj = 0; jj < 4; ++jj) {
            f32x4 vv = (jj == 0) ? vreg0 : (jj == 1) ? vreg1 : (jj == 2) ? vreg2 : vreg3;
            #pragma unroll
            for (int e = 0; e < 4; ++e)
                vtlds[buf][(vdv0 + jj * 4 + e) * 36 + vkv] = (__bf16)vv[e];
        }
    };

    float mrun = -1e30f, lrun = 0.0f;
    f32x16 o0, o1, o2, o3;
    #pragma unroll
    for (int r = 0; r < 16; ++r) { o0[r] = 0.f; o1[r] = 0.f; o2[r] = 0.f; o3[r] = 0.f; }

    stage_load(0);
    stage_write(0);

    for (int tt = 0; tt < 64; ++tt) {
        const int cur = tt & 1;
        if (tt + 1 < 64) stage_load(tt + 1);
        __syncthreads();

        f32x16 sa, sb;
        #pragma unroll
        for (int r = 0; r < 16; ++r) { sa[r] = 0.f; sb[r] = 0.f; }
        const int kswz = (l31 & 7) << 3;
        #pragma unroll
        for (int db = 0; db < 4; ++db) {
            bf16x8 kfa = *(const bf16x8*)&klds[cur][l31 * 128 + (((2*db)   * 16 + g * 8) ^ kswz)];
            sa = __builtin_amdgcn_mfma_f32_32x32x16_bf16(kfa, qf[2*db],   sa, 0, 0, 0);
            bf16x8 kfb = *(const bf16x8*)&klds[cur][l31 * 128 + (((2*db+1) * 16 + g * 8) ^ kswz)];
            sb = __builtin_amdgcn_mfma_f32_32x32x16_bf16(kfb, qf[2*db+1], sb, 0, 0, 0);
        }
        f32x16 s;
        #pragma unroll
        for (int r = 0; r < 16; ++r) s[r] = sa[r] + sb[r];

        float m8[8];
        #pragma unroll
        for (int r = 0; r < 8; ++r) m8[r] = fmaxf(s[r], s[r + 8]);
        float tmax = fmaxf(fmaxf(fmaxf(m8[0], m8[4]), fmaxf(m8[1], m8[5])),
                           fmaxf(fmaxf(m8[2], m8[6]), fmaxf(m8[3], m8[7])));
        tmax = fmaxf(tmax, __shfl_xor(tmax, 32, 64));

        if (__any(tmax > mrun + 8.0f)) {
            const float mnew  = fmaxf(mrun, tmax);
            const float alpha = __builtin_amdgcn_exp2f(mrun - mnew);
            lrun *= alpha;
            #pragma unroll
            for (int r = 0; r < 16; ++r) { o0[r] *= alpha; o1[r] *= alpha; o2[r] *= alpha; o3[r] *= alpha; }
            mrun = mnew;
        }

        float p[16];
        #pragma unroll
        for (int r = 0; r < 16; ++r) p[r] = __builtin_amdgcn_exp2f(s[r] - mrun);
        float ps0 = 0, ps1 = 0, ps2 = 0, ps3 = 0;
        #pragma unroll
        for (int r = 0; r < 4; ++r) { ps0 += p[r]; ps1 += p[r+4]; ps2 += p[r+8]; ps3 += p[r+12]; }
        lrun += ((ps0 + ps1) + (ps2 + ps3));

        bf16x8 pf0, pf1;
        #pragma unroll
        for (int e = 0; e < 8; ++e) { pf0[e] = (__bf16)p[e]; pf1[e] = (__bf16)p[8 + e]; }

        #pragma unroll
        for (int bb = 0; bb < 4; ++bb) {
            const __bf16* vb = &vtlds[cur][(bb * 32 + l31) * 36];
            bf16x4 a0 = *(const bf16x4*)(vb + 4 * g);
            bf16x4 a1 = *(const bf16x4*)(vb + 8 + 4 * g);
            bf16x8 va;
            va[0]=a0[0]; va[1]=a0[1]; va[2]=a0[2]; va[3]=a0[3];
            va[4]=a1[0]; va[5]=a1[1]; va[6]=a1[2]; va[7]=a1[3];
            f32x16& oo = (bb == 0) ? o0 : (bb == 1) ? o1 : (bb == 2) ? o2 : o3;
            oo = __builtin_amdgcn_mfma_f32_32x32x16_bf16(va, pf0, oo, 0, 0, 0);
            bf16x4 b0 = *(const bf16x4*)(vb + 16 + 4 * g);
            bf16x4 b1 = *(const bf16x4*)(vb + 24 + 4 * g);
            va[0]=b0[0]; va[1]=b0[1]; va[2]=b0[2]; va[3]=b0[3];
            va[4]=b1[0]; va[5]=b1[1]; va[6]=b1[2]; va[7]=b1[3];
            oo = __builtin_amdgcn_mfma_f32_32x32x16_bf16(va, pf1, oo, 0, 0, 0);
        }

        if (tt + 1 < 64) stage_write(cur ^ 1);
    }

    const float ltot = lrun + __shfl_xor(lrun, 32, 64);
    const float inv  = 1.0f / ltot;
    float* orow = Og + ((size_t)q * 16 + h) * 128;
    #pragma unroll
    for (int bb = 0; bb < 4; ++bb) {
        const f32x16& oo = (bb == 0) ? o0 : (bb == 1) ? o1 : (bb == 2) ? o2 : o3;
        #pragma unroll
        for (int jj = 0; jj < 4; ++jj) {
            f32x4 v;
            v[0] = oo[4*jj+0] * inv; v[1] = oo[4*jj+1] * inv;
            v[2] = oo[4*jj+2] * inv; v[3] = oo[4*jj+3] * inv;
            *(f32x4*)(orow + bb * 32 + 8 * jj + 4 * g) = v;
        }
    }
}

extern "C" void kernel_launch(void* const* d_in, const int* in_sizes, int n_in,
                              void* d_out, int out_size, void* d_ws, size_t ws_size,
                              hipStream_t stream) {
    const float* Q = (const float*)d_in[0];
    const float* K = (const float*)d_in[1];
    const float* V = (const float*)d_in[2];
    float* O = (float*)d_out;

    const size_t wsOb_b = (size_t)NSPLIT * NROWS * 128 * 2;   // 16.8 MB bf16
    const size_t wsML_b = (size_t)NSPLIT * NROWS * 2 * 4;     // 0.5 MB
    const size_t need_bytes = wsOb_b + wsML_b;

    if (ws_size >= need_bytes) {
        __bf16* wsOb = (__bf16*)d_ws;
        float*  wsML = (float*)((char*)d_ws + wsOb_b);
        hipLaunchKernelGGL(fmha_kern, dim3(256), dim3(512), 0, stream,
                           Q, K, V, wsOb, wsML);
        hipLaunchKernelGGL(fmha_combine, dim3(NROWS / 8), dim3(256), 0, stream,
                           wsOb, wsML, O);
    } else {
        hipLaunchKernelGGL(fmha_fb, dim3(256), dim3(256), 0, stream, Q, K, V, O);
    }
}